// Round 5
// baseline (365.197 us; speedup 1.0000x reference)
//
#include <hip/hip_runtime.h>
#include <stdint.h>

// irreps linear: 4 paths, out[v,i] = (1/64) * sum_u x[u,i] * w[u,v]
// mul = 4096 all paths, D in {1,3,5,7}. All tensors f32.
//
// R4 -> R5: scalar-dword weight loads capped MLP (256 B/wave-load @ 16 KB
// stride). Now: float4 loads -> 1 KB contiguous per wave-load, PF=8 deep
// (8 KB in flight/wave x 16 waves = 128 KB/CU >> 22 KB Little's law).
// Blocks: 4 paths x 16 v-tiles(256 v) x 4 u-chunks(1024 u) = 256.
// Cross-block u-combine: atomicAdd into pre-zeroed d_out (4 per address).

constexpr int MUL = 4096;
constexpr int VT  = 256;         // v per block (64 lanes x float4)
constexpr int NW  = 16;          // waves per block
constexpr int UCB = 1024;        // u per block
constexpr int UPW = UCB / NW;    // 64 u per wave
constexpr int PF  = 8;           // prefetch depth (float4)
constexpr int LDSF = 8 * 64 * 29; // reduction slab max (D=7): 59392 B

__global__ __launch_bounds__(256)
void zero_out(float* __restrict__ out) {
  out[blockIdx.x * 256 + threadIdx.x] = 0.f;
}

template<int D>
__device__ __forceinline__ void body(const float* __restrict__ w,
                                     const float* __restrict__ x,
                                     float* __restrict__ out,
                                     float* lds,
                                     int io_off, long w_off, int v0, int u_base)
{
  const int t = threadIdx.x;
  const int l = t & 63;
  const int q = t >> 6;

  // stage this block's x slice (1024 u x D) into LDS
  float* xs = lds;
  for (int j = t; j < UCB * D; j += 1024)
    xs[j] = x[io_off + u_base * D + j];
  __syncthreads();

  float acc[D][4];
  #pragma unroll
  for (int i = 0; i < D; ++i) {
    #pragma unroll
    for (int j = 0; j < 4; ++j) acc[i][j] = 0.f;
  }

  const float* wp = w + w_off + (long)(u_base + q * UPW) * MUL + v0 + l * 4;

  for (int bb = 0; bb < UPW; bb += PF) {
    float4 wv[PF];
    #pragma unroll
    for (int j = 0; j < PF; ++j)    // PF independent 16B loads in flight
      wv[j] = *reinterpret_cast<const float4*>(wp + (long)(bb + j) * MUL);
    #pragma unroll
    for (int j = 0; j < PF; ++j) {
      const float* xr = xs + (q * UPW + bb + j) * D;
      #pragma unroll
      for (int i = 0; i < D; ++i) {
        float xv = xr[i];
        acc[i][0] = fmaf(wv[j].x, xv, acc[i][0]);
        acc[i][1] = fmaf(wv[j].y, xv, acc[i][1]);
        acc[i][2] = fmaf(wv[j].z, xv, acc[i][2]);
        acc[i][3] = fmaf(wv[j].w, xv, acc[i][3]);
      }
    }
  }

  // cross-wave tree reduction via LDS (xs dead; reuse buffer).
  // per-thread slab padded to 4*D+1 floats -> stride coprime w/ 32 banks.
  constexpr int SLAB = 4 * D + 1;
  float* red = lds;
  for (int step = NW / 2; step >= 1; step >>= 1) {
    __syncthreads();               // protect xs / previous-step reads
    if (q >= step && q < 2 * step) {
      float* rp = red + ((q - step) * 64 + l) * SLAB;
      #pragma unroll
      for (int j = 0; j < 4; ++j) {
        #pragma unroll
        for (int i = 0; i < D; ++i) rp[j * D + i] = acc[i][j];
      }
    }
    __syncthreads();
    if (q < step) {
      const float* rp = red + (q * 64 + l) * SLAB;
      #pragma unroll
      for (int j = 0; j < 4; ++j) {
        #pragma unroll
        for (int i = 0; i < D; ++i) acc[i][j] += rp[j * D + i];
      }
    }
  }

  if (q == 0) {
    // out[v,i] at io_off + v*D + i ; thread covers v = v0+l*4 .. +3
    float* op = out + io_off + (size_t)(v0 + l * 4) * D;
    #pragma unroll
    for (int j = 0; j < 4; ++j) {
      #pragma unroll
      for (int i = 0; i < D; ++i)
        atomicAdd(&op[j * D + i], acc[i][j] * 0.015625f);
    }
  }
}

__global__ __launch_bounds__(1024)
void linear_main(const float* __restrict__ w, const float* __restrict__ x,
                 float* __restrict__ out)
{
  __shared__ float lds[LDSF];          // 59392 B (union: x-stage / reduction)
  const int b  = blockIdx.x;
  const int p  = b >> 6;               // 64 blocks per path
  const int r  = b & 63;
  const int v0 = (r >> 2) * VT;        // 16 v-tiles
  const int ub = (r & 3) * UCB;        // 4 u-chunks

  if      (p == 0) body<1>(w, x, out, lds,     0,         0L, v0, ub);
  else if (p == 1) body<3>(w, x, out, lds,  4096, 16777216L, v0, ub);
  else if (p == 2) body<5>(w, x, out, lds, 16384, 33554432L, v0, ub);
  else             body<7>(w, x, out, lds, 36864, 50331648L, v0, ub);
}

extern "C" void kernel_launch(void* const* d_in, const int* in_sizes, int n_in,
                              void* d_out, int out_size, void* d_ws, size_t ws_size,
                              hipStream_t stream) {
  const float* x = (const float*)d_in[0];   // 65536 f32
  const float* w = (const float*)d_in[1];   // 67108864 f32
  float* out = (float*)d_out;

  zero_out<<<256, 256, 0, stream>>>(out);
  linear_main<<<256, 1024, 0, stream>>>(w, x, out);
}